// Round 6
// baseline (452.077 us; speedup 1.0000x reference)
//
#include <hip/hip_runtime.h>
#include <math.h>

#define DIM       4096
#define NKVH      8
#define HD        128
#define MAX_SEQ   4096
#define START_POS 4080
#define NQKV      6144
#define NCHUNK    8
#define CHUNK     512
#define KS        8
#define ATT_SCALE 0.08838834764831845f

// ---- workspace layout (float offsets) ----
#define WS_PART   0           // 8*128*6144 = 6291456 (qkv partials; attn partO + oproj partials alias)
#define WS_QH     6291456     // 262144 fl = 524288 ushorts
#define WS_QL     6553600
#define WS_KNEW   6815744     // 131072
#define WS_VNEW   6946816     // 131072
#define WS_PM     7077888     // 32768
#define WS_PL     7110656     // 32768
#define WS_O      7143424     // 524288 fl (fp32 attn output; was ATH/ATL)
#define WS_PARTO  WS_PART     // 512*64*128 = 4194304 <= 6291456, stream-ordered reuse
// total = 8192000 floats = 32.8 MB

typedef __bf16 bf16x8 __attribute__((ext_vector_type(8)));
typedef float  f32x4  __attribute__((ext_vector_type(4)));
typedef unsigned int uintx4 __attribute__((ext_vector_type(4)));
typedef unsigned short ushort8v __attribute__((ext_vector_type(8)));

__device__ __forceinline__ unsigned short f2bf(float f) {
    // native RTNE conversion; compiler packs pairs into v_cvt_pk_bf16_f32
    return __builtin_bit_cast(unsigned short, (__bf16)f);
}
__device__ __forceinline__ float bf2f(unsigned short h) {
    union { unsigned int u; float f; } v; v.u = ((unsigned int)h) << 16;
    return v.f;
}
__device__ __forceinline__ void splitbf(float f, unsigned short &h, unsigned short &l) {
    h = f2bf(f);
    l = f2bf(f - bf2f(h));
}
__device__ __forceinline__ bf16x8 ldsfrag(const unsigned short* p) {
    uintx4 u = *(const uintx4*)p;
    return __builtin_bit_cast(bf16x8, u);
}
// 8B-aligned fragment load (two b64 reads) for stride-68 rows
__device__ __forceinline__ bf16x8 ldsfrag2(const unsigned short* p) {
    union { uint2 u2[2]; bf16x8 v; } u;
    u.u2[0] = *(const uint2*)p;
    u.u2[1] = *(const uint2*)(p + 4);
    return u.v;
}
#define MFMA16(a,b,c) __builtin_amdgcn_mfma_f32_16x16x32_bf16(a, b, c, 0, 0, 0)
#define VCOMP(v,j) ((j)==0?(v).x:((j)==1?(v).y:((j)==2?(v).z:(v).w)))

// ---------------- GEMM: A = fp32 (split to bf16 hi/lo in-reg), B = W fp32 -> bf16 ----------------
// r5 post-mortem restructure: NO A-LDS staging (A is L2-hot: x=8MB, O=2MB; fragments
// loaded directly from global as fp32 + split in-reg -> bit-identical values).
// Freed LDS -> DOUBLE-BUFFERED B tile, ONE barrier per K-iter (was 2):
//   iter it: [stage wreg->Bs[(it+1)&1]] [LOADW(it+2)->wreg] [compute from Bs[it&1]] [barrier]
// W loads are a full iteration in flight -> continuous memory issue, no burst+drain.
// M=128, BN=NT*16=128, BK=64, 8 iters (K-range 512 per ks). 256 thr / 4 waves.
// Epilogue: LDS-transposed float4 C-writes (r5), staged through the Bs region.
template<int NT>
__device__ __forceinline__ void gemm_body(
    const float* __restrict__ A,          // 128 x 4096 fp32 row-major
    const float* __restrict__ W, int ldW, int noff,
    float* __restrict__ part, int partStride, int ncol0, int ks,
    unsigned short* Bs)                   // 2 * (NT*16*68) ushorts
{
    constexpr int NC4   = NT * 4;         // float4 per W K-row (NT=8 -> 32 = 512B granule)
    constexpr int RSTEP = 256 / NC4;      // K-rows per 256-thread pass (8)
    constexpr int BUF   = NT * 16 * 68;   // ushorts per B buffer
    const int t = threadIdx.x;
    const int w = t >> 6, lane = t & 63, l15 = lane & 15, quad = lane >> 4;
    const int n4  = t & (NC4 - 1);
    const int kkw = t / NC4;

    f32x4 acc[2][NT];
    #pragma unroll
    for (int i = 0; i < 2; ++i)
        #pragma unroll
        for (int nt = 0; nt < NT; ++nt) acc[i][nt] = (f32x4){0.f, 0.f, 0.f, 0.f};

    const int k0base = ks * 512;
    float4 wreg[NT];

    auto LOADW = [&](int it) {
        int k0 = k0base + it * 64;
        #pragma unroll
        for (int i = 0; i < NT; ++i)
            wreg[i] = *(const float4*)(W + (size_t)(k0 + kkw + RSTEP * i) * ldW + noff + n4 * 4);
    };
    auto STAGE = [&](int buf) {
        #pragma unroll
        for (int i = 0; i < NT; ++i)
            #pragma unroll
            for (int j = 0; j < 4; ++j)
                Bs[buf * BUF + (n4 * 4 + j) * 68 + kkw + RSTEP * i] = f2bf(VCOMP(wreg[i], j));
    };

    LOADW(0);
    STAGE(0);
    LOADW(1);
    __syncthreads();

    for (int it = 0; it < 8; ++it) {
        if (it < 7) {
            STAGE((it + 1) & 1);          // stage next buffer (other waves read Bs[it&1])
            if (it < 6) LOADW(it + 2);    // keep one full iteration of W in flight
        }
        const unsigned short* Bc = Bs + (it & 1) * BUF;
        const int k0 = k0base + it * 64;
        #pragma unroll
        for (int kt = 0; kt < 2; ++kt) {
            const int kc0 = k0 + kt * 32 + quad * 8;
            bf16x8 ah[2], al[2];
            #pragma unroll
            for (int i = 0; i < 2; ++i) {
                const float* ap = A + (size_t)((2 * w + i) * 16 + l15) * 4096 + kc0;
                float4 x0 = *(const float4*)ap;
                float4 x1 = *(const float4*)(ap + 4);
                ushort8v h, l;
                unsigned short hh, ll;
                splitbf(x0.x, hh, ll); h[0] = hh; l[0] = ll;
                splitbf(x0.y, hh, ll); h[1] = hh; l[1] = ll;
                splitbf(x0.z, hh, ll); h[2] = hh; l[2] = ll;
                splitbf(x0.w, hh, ll); h[3] = hh; l[3] = ll;
                splitbf(x1.x, hh, ll); h[4] = hh; l[4] = ll;
                splitbf(x1.y, hh, ll); h[5] = hh; l[5] = ll;
                splitbf(x1.z, hh, ll); h[6] = hh; l[6] = ll;
                splitbf(x1.w, hh, ll); h[7] = hh; l[7] = ll;
                ah[i] = __builtin_bit_cast(bf16x8, h);
                al[i] = __builtin_bit_cast(bf16x8, l);
            }
            #pragma unroll
            for (int nt = 0; nt < NT; ++nt) {
                bf16x8 b = ldsfrag2(Bc + (nt * 16 + l15) * 68 + kt * 32 + quad * 8);
                acc[0][nt] = MFMA16(ah[0], b, acc[0][nt]);
                acc[0][nt] = MFMA16(al[0], b, acc[0][nt]);
                acc[1][nt] = MFMA16(ah[1], b, acc[1][nt]);
                acc[1][nt] = MFMA16(al[1], b, acc[1][nt]);
            }
        }
        __syncthreads();
    }

    // ---- LDS-transposed epilogue: 64 rows x BN staged, drained as float4 rows ----
    constexpr int BN   = NT * 16;            // 128
    constexpr int EROW = BN + 4;             // 132 floats, bank-stagger pad
    float* eps = (float*)Bs;                 // 64*132*4 = 33792 B <= 34816 B B-LDS
    #pragma unroll
    for (int i = 0; i < 2; ++i) {
        __syncthreads();
        #pragma unroll
        for (int nt = 0; nt < NT; ++nt)
            #pragma unroll
            for (int r = 0; r < 4; ++r)
                eps[(w*16 + quad*4 + r) * EROW + nt*16 + l15] = acc[i][nt][r];
        __syncthreads();
        #pragma unroll
        for (int s = 0; s < (64 * NC4) / 256; ++s) {   // 8 float4 per thread
            int idx  = t + s * 256;                    // 0..2047
            int lrow = idx / NC4;                      // 0..63
            int c4   = idx & (NC4 - 1);                // 0..31
            int grow = (2 * (lrow >> 4) + i) * 16 + (lrow & 15);
            f32x4 v = *(const f32x4*)&eps[lrow * EROW + c4 * 4];
            *(f32x4*)&part[(size_t)(ks * 128 + grow) * partStride + ncol0 + c4 * 4] = v;
        }
    }
}

__global__ __launch_bounds__(256, 2) void qkv_gemm_kernel(
    const float* __restrict__ x,
    const float* __restrict__ Wq, const float* __restrict__ Wk,
    const float* __restrict__ Wv, float* __restrict__ part)
{
    __shared__ __align__(16) unsigned short Bs[2 * 128 * 68];   // 34816 B
    int ncol0 = blockIdx.x * 128;
    int ks = blockIdx.y;
    const float* W; int ldW, noff;
    if (ncol0 < 4096)      { W = Wq; ldW = 4096; noff = ncol0; }
    else if (ncol0 < 5120) { W = Wk; ldW = 1024; noff = ncol0 - 4096; }
    else                   { W = Wv; ldW = 1024; noff = ncol0 - 5120; }
    gemm_body<8>(x, W, ldW, noff, part, NQKV, ncol0, ks, Bs);
}

__global__ __launch_bounds__(256, 2) void oproj_gemm_kernel(
    const float* __restrict__ O, const float* __restrict__ Wo,
    float* __restrict__ part)
{
    __shared__ __align__(16) unsigned short Bs[2 * 128 * 68];
    int ncol0 = blockIdx.x * 128;
    int ks = blockIdx.y;
    gemm_body<8>(O, Wo, 4096, ncol0, part, 4096, ncol0, ks, Bs);
}

__global__ __launch_bounds__(256) void qkv_reduce_kernel(
    const float* __restrict__ part, const float* __restrict__ bq,
    const float* __restrict__ bk, const float* __restrict__ bv,
    unsigned short* __restrict__ qh, unsigned short* __restrict__ ql,
    float* __restrict__ k_new, float* __restrict__ v_new)
{
    int gid = blockIdx.x * 256 + threadIdx.x;     // < 128*1536 (float4 units)
    int row = gid / 1536;
    int c4  = gid - row * 1536;
    int n = c4 * 4;
    float4 s = make_float4(0.f, 0.f, 0.f, 0.f);
    #pragma unroll
    for (int j = 0; j < KS; ++j) {
        float4 p = *(const float4*)&part[(size_t)(j * 128 + row) * NQKV + n];
        s.x += p.x; s.y += p.y; s.z += p.z; s.w += p.w;
    }
    if (n < 4096) {
        float4 b4 = *(const float4*)&bq[n];
        ushort4 h, l;
        splitbf(s.x + b4.x, h.x, l.x);
        splitbf(s.y + b4.y, h.y, l.y);
        splitbf(s.z + b4.z, h.z, l.z);
        splitbf(s.w + b4.w, h.w, l.w);
        *(ushort4*)&qh[row * 4096 + n] = h;
        *(ushort4*)&ql[row * 4096 + n] = l;
    } else if (n < 5120) {
        float4 b4 = *(const float4*)&bk[n - 4096];
        float4 o = make_float4(s.x + b4.x, s.y + b4.y, s.z + b4.z, s.w + b4.w);
        *(float4*)&k_new[row * 1024 + (n - 4096)] = o;
    } else {
        float4 b4 = *(const float4*)&bv[n - 5120];
        float4 o = make_float4(s.x + b4.x, s.y + b4.y, s.z + b4.z, s.w + b4.w);
        *(float4*)&v_new[row * 1024 + (n - 5120)] = o;
    }
}

// ---------------- MFMA flash-decoding attention (bf16 K/V/P, split-bf16 Q) ----------------
// Round-3 structure, untouched (best measured: 91-96 us).
// 1KB-granule: block = (b*4 + gg)*8 + chunk(512 pos), gg = KV-head PAIR; each staging
// instruction reads one position's 2-head 1KB span contiguously.
// 512 threads / 8 waves: wave w -> (gsel = w>>2, rep = w&3); each wave covers the FULL
// 512-pos chunk for its (g = gg*2+gsel, rep) head -> no in-block merge needed.
// Single-buffer prefetch, statically indexed kreg[4]/vreg[4] (rule #20).
// pos-slot permutation pi(pos) = (pos&7)*4 + (pos>>3), applied to BOTH P and V^T.
__global__ __launch_bounds__(512, 2) void attn_partial5_kernel(
    const unsigned short* __restrict__ qhp, const unsigned short* __restrict__ qlp,
    const float* __restrict__ kc, const float* __restrict__ vc,
    const float* __restrict__ knew, const float* __restrict__ vnew,
    float* __restrict__ part_O, float* __restrict__ part_m, float* __restrict__ part_l)
{
    __shared__ unsigned short Kb[2][32][136];   // [g][pos][d]  17408 B
    __shared__ unsigned short Vt[2][128][44];   // [g][d][slot] 22528 B (pad 44)
    __shared__ unsigned short Pw[8][16 * 36];   // per-wave P   9216 B

    const int t = threadIdx.x;
    const int w = t >> 6, lane = t & 63, l15 = lane & 15, quad = lane >> 4;
    const int gsel = w >> 2;          // which head of the pair
    const int rep  = w & 3;           // rep-head within group
    const int blk = blockIdx.x;
    const int b = blk >> 5, gg = (blk >> 3) & 3, c = blk & 7;
    const int g = gg * 2 + gsel;

    // staging coords: wave w stages pos {w, w+8, w+16, w+24}; lane = float4 within 1KB pos-row
    const int p0 = t >> 6;            // = w (uniform per wave)
    const int q4 = t & 63;            // float4 index within [2g][128d] row
    const int gl = q4 >> 5;           // g-half this thread stages
    const int d0 = (q4 & 31) << 2;    // d offset

    bf16x8 qhf[4], qlf[4];
    {
        size_t base = (size_t)(b * 16 + l15) * DIM + (g * 4 + rep) * HD + quad * 8;
        #pragma unroll
        for (int kt = 0; kt < 4; ++kt) {
            qhf[kt] = ldsfrag(qhp + base + kt * 32);
            qlf[kt] = ldsfrag(qlp + base + kt * 32);
        }
    }

    float m_run[4], l_run[4];
    f32x4 oacc[8];
    #pragma unroll
    for (int r = 0; r < 4; ++r) { m_run[r] = -INFINITY; l_run[r] = 0.f; }
    #pragma unroll
    for (int d = 0; d < 8; ++d) oacc[d] = (f32x4){0.f, 0.f, 0.f, 0.f};

    float4 kreg[4], vreg[4];          // single buffer, static indices only
    auto LOADKV = [&](int it) {
        #pragma unroll
        for (int i = 0; i < 4; ++i) {
            int pos = p0 + i * 8;
            int pg = c * CHUNK + it * 32 + pos;
            const float *ksrc, *vsrc;
            if (pg >= START_POS) {
                size_t off = (size_t)(b * 16 + pg - START_POS) * (NKVH * HD) + gg * 256 + q4 * 4;
                ksrc = knew + off; vsrc = vnew + off;
            } else {
                size_t off = ((size_t)(b * MAX_SEQ + pg) * NKVH) * HD + gg * 256 + q4 * 4;
                ksrc = kc + off; vsrc = vc + off;
            }
            kreg[i] = *(const float4*)ksrc;
            vreg[i] = *(const float4*)vsrc;
        }
    };

    unsigned short* phw = Pw[w];

    LOADKV(0);
    for (int it = 0; it < 16; ++it) {            // 16 iters x 32 pos = 512 pos
        __syncthreads();
        // K: [g][pos][d], b64 writes; wave's lanes cover one pos-pair-row contiguously
        #pragma unroll
        for (int i = 0; i < 4; ++i) {
            int pos = p0 + i * 8;
            ushort4 k4 = make_ushort4(f2bf(kreg[i].x), f2bf(kreg[i].y),
                                      f2bf(kreg[i].z), f2bf(kreg[i].w));
            *(ushort4*)&Kb[gl][pos][d0] = k4;
        }
        // V: register-gather transpose. Thread holds pos = p0+8i (i=0..3) at fixed (gl,d0).
        // slot(pos) = (pos&7)*4 + (pos>>3) => thread's 4 pos -> slots p0*4..p0*4+3.
        #pragma unroll
        for (int j = 0; j < 4; ++j) {
            ushort4 v4 = make_ushort4(f2bf(VCOMP(vreg[0], j)), f2bf(VCOMP(vreg[1], j)),
                                      f2bf(VCOMP(vreg[2], j)), f2bf(VCOMP(vreg[3], j)));
            *(ushort4*)&Vt[gl][d0 + j][p0 * 4] = v4;
        }
        __syncthreads();
        if (it + 1 < 16) LOADKV(it + 1);         // overlaps with compute below

        // S = Q K^T (2 n-tiles x 4 k-steps x {hi,lo})
        f32x4 sacc[2];
        sacc[0] = (f32x4){0.f,0.f,0.f,0.f};
        sacc[1] = (f32x4){0.f,0.f,0.f,0.f};
        #pragma unroll
        for (int nt = 0; nt < 2; ++nt)
            #pragma unroll
            for (int kt = 0; kt < 4; ++kt) {
                bf16x8 bh = ldsfrag(&Kb[gsel][nt*16 + l15][kt*32 + quad*8]);
                sacc[nt] = MFMA16(qhf[kt], bh, sacc[nt]);
                sacc[nt] = MFMA16(qlf[kt], bh, sacc[nt]);
            }

        // online softmax; q-row = quad*4+r across the quad's 16 lanes
        float e0[4], e1[4], alpha[4];
        #pragma unroll
        for (int r = 0; r < 4; ++r) {
            float s0 = sacc[0][r] * ATT_SCALE;
            float s1 = sacc[1][r] * ATT_SCALE;
            float mx = fmaxf(s0, s1);
            mx = fmaxf(mx, __shfl_xor(mx, 1));
            mx = fmaxf(mx, __shfl_xor(mx, 2));
            mx = fmaxf(mx, __shfl_xor(mx, 4));
            mx = fmaxf(mx, __shfl_xor(mx, 8));
            float mnew = fmaxf(m_run[r], mx);
            alpha[r] = __expf(m_run[r] - mnew);
            e0[r] = __expf(s0 - mnew);
            e1[r] = __expf(s1 - mnew);
            float sum = e0[r] + e1[r];
            sum += __shfl_xor(sum, 1);
            sum += __shfl_xor(sum, 2);
            sum += __shfl_xor(sum, 4);
            sum += __shfl_xor(sum, 8);
            l_run[r] = l_run[r] * alpha[r] + sum;
            m_run[r] = mnew;
        }
        #pragma unroll
        for (int d = 0; d < 8; ++d)
            #pragma unroll
            for (int r = 0; r < 4; ++r) oacc[d][r] *= alpha[r];

        // P -> per-wave LDS at permuted slots: slot = 4*(l15&7) + 2*nt + (l15>>3)
        {
            int slot0 = 4 * (l15 & 7) + (l15 >> 3);
            #pragma unroll
            for (int r = 0; r < 4; ++r) {
                phw[(quad*4 + r) * 36 + slot0]     = f2bf(e0[r]);
                phw[(quad*4 + r) * 36 + slot0 + 2] = f2bf(e1[r]);
            }
        }
        bf16x8 pa = ldsfrag(phw + l15 * 36 + quad * 8);

        // O += P V (8 d-tiles)
        #pragma unroll
        for (int dt = 0; dt < 8; ++dt) {
            bf16x8 vb = ldsfrag(&Vt[gsel][dt*16 + l15][quad * 8]);
            oacc[dt] = MFMA16(pa, vb, oacc[dt]);
        }
    }

    // each wave owns its (g, rep) head over the full chunk: write partials directly
    const size_t obase = (size_t)((b * 8 + g) * 8 + c) * 64 + rep * 16 + quad * 4;
    #pragma unroll
    for (int dt = 0; dt < 8; ++dt)
        #pragma unroll
        for (int r = 0; r < 4; ++r)
            part_O[(obase + r) * HD + dt * 16 + l15] = oacc[dt][r];
    if (l15 == 0) {
        #pragma unroll
        for (int r = 0; r < 4; ++r) {
            part_m[obase + r] = m_run[r];
            part_l[obase + r] = l_run[r];
        }
    }
}

__global__ __launch_bounds__(128) void attn_combine_kernel(
    const float* __restrict__ part_O, const float* __restrict__ part_m,
    const float* __restrict__ part_l, float* __restrict__ O)
{
    int bid = blockIdx.x;          // (b*8+g)*64 + row
    int d = threadIdx.x;
    int bg = bid >> 6;
    int row = bid & 63;
    float mc[NCHUNK], lc[NCHUNK];
    float M = -INFINITY;
    #pragma unroll
    for (int cc = 0; cc < NCHUNK; ++cc) {
        mc[cc] = part_m[(bg * NCHUNK + cc) * 64 + row];
        lc[cc] = part_l[(bg * NCHUNK + cc) * 64 + row];
        M = fmaxf(M, mc[cc]);
    }
    float L = 0.f, acc = 0.f;
    #pragma unroll
    for (int cc = 0; cc < NCHUNK; ++cc) {
        float wgt = __expf(mc[cc] - M);
        L += lc[cc] * wgt;
        acc += part_O[((size_t)(bg * NCHUNK + cc) * 64 + row) * HD + d] * wgt;
    }
    int b = bg >> 3, g = bg & 7;
    int r = row >> 4, qp = row & 15;
    // fp32 attn output; oproj_gemm splits to bf16 hi/lo in-reg (same values as before)
    O[(size_t)(b * 16 + qp) * DIM + (g * 4 + r) * HD + d] = acc / L;
}

__global__ __launch_bounds__(256) void oproj_reduce_kernel(
    const float* __restrict__ part, const float* __restrict__ bo,
    float* __restrict__ out)
{
    int gid4 = blockIdx.x * 256 + threadIdx.x;   // < 128*1024 (float4 units)
    int n = (gid4 & 1023) * 4;
    float4 s = make_float4(0.f, 0.f, 0.f, 0.f);
    #pragma unroll
    for (int j = 0; j < KS; ++j) {
        float4 p = *(const float4*)&part[(size_t)j * 524288 + (size_t)gid4 * 4];
        s.x += p.x; s.y += p.y; s.z += p.z; s.w += p.w;
    }
    float4 b4 = *(const float4*)&bo[n];
    float4 o = make_float4(s.x + b4.x, s.y + b4.y, s.z + b4.z, s.w + b4.w);
    *(float4*)&out[(size_t)gid4 * 4] = o;
}

extern "C" void kernel_launch(void* const* d_in, const int* in_sizes, int n_in,
                              void* d_out, int out_size, void* d_ws, size_t ws_size,
                              hipStream_t stream)
{
    const float* x  = (const float*)d_in[0];
    const float* kc = (const float*)d_in[1];
    const float* vc = (const float*)d_in[2];
    const float* Wq = (const float*)d_in[3];
    const float* bq = (const float*)d_in[4];
    const float* Wk = (const float*)d_in[5];
    const float* bk = (const float*)d_in[6];
    const float* Wv = (const float*)d_in[7];
    const float* bv = (const float*)d_in[8];
    const float* Wo = (const float*)d_in[9];
    const float* bo = (const float*)d_in[10];
    float* out = (float*)d_out;
    float* ws  = (float*)d_ws;

    unsigned short* qh = (unsigned short*)(ws + WS_QH);
    unsigned short* ql = (unsigned short*)(ws + WS_QL);
    float* O = ws + WS_O;

    qkv_gemm_kernel<<<dim3(48, KS), 256, 0, stream>>>(x, Wq, Wk, Wv, ws + WS_PART);
    qkv_reduce_kernel<<<768, 256, 0, stream>>>(ws + WS_PART, bq, bk, bv,
                                               qh, ql, ws + WS_KNEW, ws + WS_VNEW);
    attn_partial5_kernel<<<256, 512, 0, stream>>>(qh, ql, kc, vc,
                                                  ws + WS_KNEW, ws + WS_VNEW,
                                                  ws + WS_PARTO, ws + WS_PM, ws + WS_PL);
    attn_combine_kernel<<<4096, 128, 0, stream>>>(ws + WS_PARTO, ws + WS_PM,
                                                  ws + WS_PL, O);
    oproj_gemm_kernel<<<dim3(32, KS), 256, 0, stream>>>(O, Wo, ws + WS_PART);
    oproj_reduce_kernel<<<512, 256, 0, stream>>>(ws + WS_PART, bo, out);
}

// Round 7
// 435.826 us; speedup vs baseline: 1.0373x; 1.0373x over previous
//
#include <hip/hip_runtime.h>
#include <math.h>

#define DIM       4096
#define NKVH      8
#define HD        128
#define MAX_SEQ   4096
#define START_POS 4080
#define NQKV      6144
#define NCHUNK    8
#define CHUNK     512
#define KS        8
#define ATT_SCALE 0.08838834764831845f

// ---- workspace layout (float offsets) ----
#define WS_PART   0           // 8*128*6144 = 6291456 (qkv partials; attn partO + oproj partials alias)
#define WS_QH     6291456     // 262144 fl = 524288 ushorts
#define WS_QL     6553600
#define WS_KNEW   6815744     // 131072
#define WS_VNEW   6946816     // 131072
#define WS_PM     7077888     // 32768
#define WS_PL     7110656     // 32768
#define WS_ATH    7143424     // 262144
#define WS_ATL    7405568     // 262144
#define WS_XH     7667712     // 262144
#define WS_XL     7929856     // 262144
#define WS_PARTO  WS_PART     // 512*64*128 = 4194304 <= 6291456, stream-ordered reuse
// total = 8192000 floats = 32.8 MB

typedef __bf16 bf16x8 __attribute__((ext_vector_type(8)));
typedef float  f32x4  __attribute__((ext_vector_type(4)));
typedef unsigned int uintx4 __attribute__((ext_vector_type(4)));

__device__ __forceinline__ unsigned short f2bf(float f) {
    // native RTNE conversion (bit-identical to the +0x7FFF rounding twiddle)
    return __builtin_bit_cast(unsigned short, (__bf16)f);
}
__device__ __forceinline__ float bf2f(unsigned short h) {
    union { unsigned int u; float f; } v; v.u = ((unsigned int)h) << 16;
    return v.f;
}
__device__ __forceinline__ void splitbf(float f, unsigned short &h, unsigned short &l) {
    h = f2bf(f);
    l = f2bf(f - bf2f(h));
}
__device__ __forceinline__ bf16x8 ldsfrag(const unsigned short* p) {
    uintx4 u = *(const uintx4*)p;
    return __builtin_bit_cast(bf16x8, u);
}
// 8B-aligned fragment load (two b64 reads) for rows whose stride is 8-mod-16 bytes
__device__ __forceinline__ bf16x8 ldsfrag2(const unsigned short* p) {
    union { uint2 u2[2]; bf16x8 v; } u;
    u.u2[0] = *(const uint2*)p;
    u.u2[1] = *(const uint2*)(p + 4);
    return u.v;
}
#define MFMA16(a,b,c) __builtin_amdgcn_mfma_f32_16x16x32_bf16(a, b, c, 0, 0, 0)
#define VCOMP(v,j) ((j)==0?(v).x:((j)==1?(v).y:((j)==2?(v).z:(v).w)))

// ---------------- split x -> bf16 hi/lo (float4 vectorized) ----------------
__global__ __launch_bounds__(256) void split_x_kernel(
    const float* __restrict__ x, unsigned short* __restrict__ xh,
    unsigned short* __restrict__ xl, int n4)
{
    int i = blockIdx.x * 256 + threadIdx.x;      // float4 index
    if (i < n4) {
        float4 v = *(const float4*)(x + (size_t)i * 4);
        ushort4 h, l;
        splitbf(v.x, h.x, l.x);
        splitbf(v.y, h.y, l.y);
        splitbf(v.z, h.z, l.z);
        splitbf(v.w, h.w, l.w);
        *(ushort4*)(xh + (size_t)i * 4) = h;
        *(ushort4*)(xl + (size_t)i * 4) = l;
    }
}

// ---------------- GEMM: A = split-bf16 (hi/lo), B = W fp32 -> plain bf16 ----------------
// Round-0 structure verbatim (measured-best non-attn config across 7 rounds):
// M=128, BN=64, BK=64, 8 K-iters of 64 (K-range 512 per ks). 256 thr / 4 waves.
// wave w: m-tiles {2w,2w+1} x 4 n-tiles; 2 MFMA per product (Ah*B + Al*B).
__device__ __forceinline__ void gemm_body(
    const unsigned short* __restrict__ Ah, const unsigned short* __restrict__ Al,
    const float* __restrict__ W, int ldW, int noff,
    float* __restrict__ part, int partStride, int ncol0, int ks,
    unsigned short* Ahs, unsigned short* Als, unsigned short* Bs)
{
    const int t = threadIdx.x;
    const int w = t >> 6, lane = t & 63, l15 = lane & 15, quad = lane >> 4;
    f32x4 acc[2][4];
    #pragma unroll
    for (int i = 0; i < 2; ++i)
        #pragma unroll
        for (int nt = 0; nt < 4; ++nt) acc[i][nt] = (f32x4){0.f, 0.f, 0.f, 0.f};

    const int k0base = ks * 512;
    uintx4 areg_h[4], areg_l[4];
    float4 wreg[4];

    auto LOAD = [&](int it) {
        int k0 = k0base + it * 64;
        #pragma unroll
        for (int i = 0; i < 4; ++i) {
            int f = t + i * 256;                 // 128x64 A tile = 1024 x8-vectors
            int row = f >> 3, c0 = (f & 7) << 3;
            size_t off = (size_t)row * DIM + k0 + c0;
            areg_h[i] = *(const uintx4*)(Ah + off);
            areg_l[i] = *(const uintx4*)(Al + off);
        }
        #pragma unroll
        for (int i = 0; i < 4; ++i) {
            int kk = (t >> 4) + 16 * i;          // 64x64 W tile = 1024 float4
            int n0 = (t & 15) << 2;
            wreg[i] = *(const float4*)(W + (size_t)(k0 + kk) * ldW + noff + n0);
        }
    };

    LOAD(0);
    for (int it = 0; it < 8; ++it) {
        __syncthreads();
        #pragma unroll
        for (int i = 0; i < 4; ++i) {
            int f = t + i * 256;
            int row = f >> 3, c0 = (f & 7) << 3;
            *(uintx4*)(Ahs + row * 72 + c0) = areg_h[i];
            *(uintx4*)(Als + row * 72 + c0) = areg_l[i];
        }
        {
            int n0 = (t & 15) << 2;
            #pragma unroll
            for (int i = 0; i < 4; ++i) {
                int kk = (t >> 4) + 16 * i;
                #pragma unroll
                for (int j = 0; j < 4; ++j)
                    Bs[(n0 + j) * 68 + kk] = f2bf(VCOMP(wreg[i], j));   // [n][k]
            }
        }
        __syncthreads();
        if (it < 7) LOAD(it + 1);
        #pragma unroll
        for (int kt = 0; kt < 2; ++kt) {
            int ko = kt * 32 + quad * 8;
            bf16x8 ah0 = ldsfrag(Ahs + ((2*w+0)*16 + l15) * 72 + ko);
            bf16x8 ah1 = ldsfrag(Ahs + ((2*w+1)*16 + l15) * 72 + ko);
            bf16x8 al0 = ldsfrag(Als + ((2*w+0)*16 + l15) * 72 + ko);
            bf16x8 al1 = ldsfrag(Als + ((2*w+1)*16 + l15) * 72 + ko);
            #pragma unroll
            for (int nt = 0; nt < 4; ++nt) {
                bf16x8 b = ldsfrag2(Bs + (nt*16 + l15) * 68 + ko);
                acc[0][nt] = MFMA16(ah0, b, acc[0][nt]);
                acc[0][nt] = MFMA16(al0, b, acc[0][nt]);
                acc[1][nt] = MFMA16(ah1, b, acc[1][nt]);
                acc[1][nt] = MFMA16(al1, b, acc[1][nt]);
            }
        }
    }
    #pragma unroll
    for (int i = 0; i < 2; ++i)
        #pragma unroll
        for (int nt = 0; nt < 4; ++nt)
            #pragma unroll
            for (int r = 0; r < 4; ++r) {
                int row = (2*w + i) * 16 + quad * 4 + r;     // C/D: row=quad*4+reg
                int col = ncol0 + nt * 16 + l15;             //      col=lane&15
                part[(size_t)(ks * 128 + row) * partStride + col] = acc[i][nt][r];
            }
}

__global__ __launch_bounds__(256) void qkv_gemm_kernel(
    const unsigned short* __restrict__ xh, const unsigned short* __restrict__ xl,
    const float* __restrict__ Wq, const float* __restrict__ Wk,
    const float* __restrict__ Wv, float* __restrict__ part)
{
    __shared__ unsigned short Ahs[128 * 72], Als[128 * 72];
    __shared__ unsigned short Bs[64 * 68];
    int ncol0 = blockIdx.x * 64;
    int ks = blockIdx.y;
    const float* W; int ldW, noff;
    if (ncol0 < 4096)      { W = Wq; ldW = 4096; noff = ncol0; }
    else if (ncol0 < 5120) { W = Wk; ldW = 1024; noff = ncol0 - 4096; }
    else                   { W = Wv; ldW = 1024; noff = ncol0 - 5120; }
    gemm_body(xh, xl, W, ldW, noff, part, NQKV, ncol0, ks, Ahs, Als, Bs);
}

__global__ __launch_bounds__(256) void oproj_gemm_kernel(
    const unsigned short* __restrict__ ah, const unsigned short* __restrict__ al,
    const float* __restrict__ Wo, float* __restrict__ part)
{
    __shared__ unsigned short Ahs[128 * 72], Als[128 * 72];
    __shared__ unsigned short Bs[64 * 68];
    int ncol0 = blockIdx.x * 64;
    int ks = blockIdx.y;
    gemm_body(ah, al, Wo, 4096, ncol0, part, 4096, ncol0, ks, Ahs, Als, Bs);
}

__global__ __launch_bounds__(256) void qkv_reduce_kernel(
    const float* __restrict__ part, const float* __restrict__ bq,
    const float* __restrict__ bk, const float* __restrict__ bv,
    unsigned short* __restrict__ qh, unsigned short* __restrict__ ql,
    float* __restrict__ k_new, float* __restrict__ v_new)
{
    int gid = blockIdx.x * 256 + threadIdx.x;     // < 128*1536 (float4 units)
    int row = gid / 1536;
    int c4  = gid - row * 1536;
    int n = c4 * 4;
    float4 s = make_float4(0.f, 0.f, 0.f, 0.f);
    #pragma unroll
    for (int j = 0; j < KS; ++j) {
        float4 p = *(const float4*)&part[(size_t)(j * 128 + row) * NQKV + n];
        s.x += p.x; s.y += p.y; s.z += p.z; s.w += p.w;
    }
    if (n < 4096) {
        float4 b4 = *(const float4*)&bq[n];
        ushort4 h, l;
        splitbf(s.x + b4.x, h.x, l.x);
        splitbf(s.y + b4.y, h.y, l.y);
        splitbf(s.z + b4.z, h.z, l.z);
        splitbf(s.w + b4.w, h.w, l.w);
        *(ushort4*)&qh[row * 4096 + n] = h;
        *(ushort4*)&ql[row * 4096 + n] = l;
    } else if (n < 5120) {
        float4 b4 = *(const float4*)&bk[n - 4096];
        float4 o = make_float4(s.x + b4.x, s.y + b4.y, s.z + b4.z, s.w + b4.w);
        *(float4*)&k_new[row * 1024 + (n - 4096)] = o;
    } else {
        float4 b4 = *(const float4*)&bv[n - 5120];
        float4 o = make_float4(s.x + b4.x, s.y + b4.y, s.z + b4.z, s.w + b4.w);
        *(float4*)&v_new[row * 1024 + (n - 5120)] = o;
    }
}

// ---------------- MFMA flash-decoding attention (bf16 K/V/P, split-bf16 Q) ----------------
// r6 post-mortem change: 64-pos K/V tiles (8 iters instead of 16) -> HALF the barrier
// phases per chunk. Per-phase overhead (~10k cyc/iter observed vs ~3k critical path) is
// the measured limiter; bytes & MFMA per phase double, phase count halves.
// 1KB-granule kept: block = (b*4 + gg)*8 + chunk(512 pos), gg = KV-head PAIR; each wave
// stages whole 2-head 1KB position rows. Wave w -> (gsel = w>>2, rep = w&3), covers the
// FULL chunk for its (g, rep) head -> no in-block merge.
// pos-slot permutation pi(pos) = (pos&7)*8 + (pos>>3), applied to BOTH P and V^T.
// Vt/Pw row stride 76 ushorts (152B = 6 banks mod 32): 16 lanes at stride-6 hit 16
// distinct banks -> conflict-free PV reads.
__global__ __launch_bounds__(512, 2) void attn_partial7_kernel(
    const unsigned short* __restrict__ qhp, const unsigned short* __restrict__ qlp,
    const float* __restrict__ kc, const float* __restrict__ vc,
    const float* __restrict__ knew, const float* __restrict__ vnew,
    float* __restrict__ part_O, float* __restrict__ part_m, float* __restrict__ part_l)
{
    __shared__ unsigned short Kb[2][64][136];   // [g][pos][d]   34816 B
    __shared__ unsigned short Vt[2][128][76];   // [g][d][slot]  38912 B
    __shared__ unsigned short Pw[8][16 * 76];   // per-wave P    19456 B  (total ~91 KB, 1 blk/CU)

    const int t = threadIdx.x;
    const int w = t >> 6, lane = t & 63, l15 = lane & 15, quad = lane >> 4;
    const int gsel = w >> 2;          // which head of the pair
    const int rep  = w & 3;           // rep-head within group
    const int blk = blockIdx.x;
    const int b = blk >> 5, gg = (blk >> 3) & 3, c = blk & 7;
    const int g = gg * 2 + gsel;

    // staging coords: wave w stages pos {w, w+8, ..., w+56}; lane = float4 within 1KB pos-row
    const int p0 = t >> 6;            // = w (uniform per wave)
    const int q4 = t & 63;            // float4 index within [2g][128d] row
    const int gl = q4 >> 5;           // g-half this thread stages
    const int d0 = (q4 & 31) << 2;    // d offset

    bf16x8 qhf[4], qlf[4];
    {
        size_t base = (size_t)(b * 16 + l15) * DIM + (g * 4 + rep) * HD + quad * 8;
        #pragma unroll
        for (int kt = 0; kt < 4; ++kt) {
            qhf[kt] = ldsfrag(qhp + base + kt * 32);
            qlf[kt] = ldsfrag(qlp + base + kt * 32);
        }
    }

    float m_run[4], l_run[4];
    f32x4 oacc[8];
    #pragma unroll
    for (int r = 0; r < 4; ++r) { m_run[r] = -INFINITY; l_run[r] = 0.f; }
    #pragma unroll
    for (int d = 0; d < 8; ++d) oacc[d] = (f32x4){0.f, 0.f, 0.f, 0.f};

    float4 kreg[8], vreg[8];          // single buffer, static indices only (rule #20)
    auto LOADKV = [&](int it) {       // it = 64-pos tile index, 0..7
        #pragma unroll
        for (int i = 0; i < 8; ++i) {
            int pos = p0 + i * 8;
            int pg = c * CHUNK + it * 64 + pos;
            const float *ksrc, *vsrc;
            if (pg >= START_POS) {
                size_t off = (size_t)(b * 16 + pg - START_POS) * (NKVH * HD) + gg * 256 + q4 * 4;
                ksrc = knew + off; vsrc = vnew + off;
            } else {
                size_t off = ((size_t)(b * MAX_SEQ + pg) * NKVH) * HD + gg * 256 + q4 * 4;
                ksrc = kc + off; vsrc = vc + off;
            }
            kreg[i] = *(const float4*)ksrc;
            vreg[i] = *(const float4*)vsrc;
        }
    };

    unsigned short* phw = Pw[w];
    const int slotbase = (l15 & 7) * 8 + (l15 >> 3);   // + 2*nt for S-col nt*16+l15

    LOADKV(0);
    for (int it = 0; it < 8; ++it) {             // 8 iters x 64 pos = 512 pos
        __syncthreads();
        // K: [g][pos][d], b64 writes; wave's lanes cover one pos-pair-row contiguously
        #pragma unroll
        for (int i = 0; i < 8; ++i) {
            int pos = p0 + i * 8;
            ushort4 k4 = make_ushort4(f2bf(kreg[i].x), f2bf(kreg[i].y),
                                      f2bf(kreg[i].z), f2bf(kreg[i].w));
            *(ushort4*)&Kb[gl][pos][d0] = k4;
        }
        // V: register-gather transpose. Thread holds pos = p0+8i (i=0..7) at fixed (gl,d0).
        // slot(pos) = (pos&7)*8 + (pos>>3) => thread's 8 pos -> slots p0*8..p0*8+7.
        #pragma unroll
        for (int j = 0; j < 4; ++j) {
            ushort4 vlo = make_ushort4(f2bf(VCOMP(vreg[0], j)), f2bf(VCOMP(vreg[1], j)),
                                       f2bf(VCOMP(vreg[2], j)), f2bf(VCOMP(vreg[3], j)));
            ushort4 vhi = make_ushort4(f2bf(VCOMP(vreg[4], j)), f2bf(VCOMP(vreg[5], j)),
                                       f2bf(VCOMP(vreg[6], j)), f2bf(VCOMP(vreg[7], j)));
            *(ushort4*)&Vt[gl][d0 + j][p0 * 8]     = vlo;
            *(ushort4*)&Vt[gl][d0 + j][p0 * 8 + 4] = vhi;
        }
        __syncthreads();
        if (it + 1 < 8) LOADKV(it + 1);          // in flight across the whole compute phase

        // S = Q K^T (4 n-tiles x 4 k-steps x {hi,lo})
        f32x4 sacc[4];
        #pragma unroll
        for (int nt = 0; nt < 4; ++nt) sacc[nt] = (f32x4){0.f,0.f,0.f,0.f};
        #pragma unroll
        for (int nt = 0; nt < 4; ++nt)
            #pragma unroll
            for (int kt = 0; kt < 4; ++kt) {
                bf16x8 bh = ldsfrag(&Kb[gsel][nt*16 + l15][kt*32 + quad*8]);
                sacc[nt] = MFMA16(qhf[kt], bh, sacc[nt]);
                sacc[nt] = MFMA16(qlf[kt], bh, sacc[nt]);
            }

        // online softmax over 64 positions; q-row = quad*4+r across the quad's 16 lanes
        float e0[4], e1[4], e2[4], e3[4], alpha[4];
        #pragma unroll
        for (int r = 0; r < 4; ++r) {
            float s0 = sacc[0][r] * ATT_SCALE;
            float s1 = sacc[1][r] * ATT_SCALE;
            float s2 = sacc[2][r] * ATT_SCALE;
            float s3 = sacc[3][r] * ATT_SCALE;
            float mx = fmaxf(fmaxf(s0, s1), fmaxf(s2, s3));
            mx = fmaxf(mx, __shfl_xor(mx, 1));
            mx = fmaxf(mx, __shfl_xor(mx, 2));
            mx = fmaxf(mx, __shfl_xor(mx, 4));
            mx = fmaxf(mx, __shfl_xor(mx, 8));
            float mnew = fmaxf(m_run[r], mx);
            alpha[r] = __expf(m_run[r] - mnew);
            e0[r] = __expf(s0 - mnew);
            e1[r] = __expf(s1 - mnew);
            e2[r] = __expf(s2 - mnew);
            e3[r] = __expf(s3 - mnew);
            float sum = (e0[r] + e1[r]) + (e2[r] + e3[r]);
            sum += __shfl_xor(sum, 1);
            sum += __shfl_xor(sum, 2);
            sum += __shfl_xor(sum, 4);
            sum += __shfl_xor(sum, 8);
            l_run[r] = l_run[r] * alpha[r] + sum;
            m_run[r] = mnew;
        }
        #pragma unroll
        for (int d = 0; d < 8; ++d)
            #pragma unroll
            for (int r = 0; r < 4; ++r) oacc[d][r] *= alpha[r];

        // P -> per-wave LDS at permuted slots: slot = slotbase + 2*nt
        #pragma unroll
        for (int r = 0; r < 4; ++r) {
            unsigned short* pr = phw + (quad*4 + r) * 76 + slotbase;
            pr[0] = f2bf(e0[r]);
            pr[2] = f2bf(e1[r]);
            pr[4] = f2bf(e2[r]);
            pr[6] = f2bf(e3[r]);
        }
        bf16x8 pa0 = ldsfrag2(phw + l15 * 76 + quad * 8);
        bf16x8 pa1 = ldsfrag2(phw + l15 * 76 + 32 + quad * 8);

        // O += P V (8 d-tiles x 2 k-steps over 64 slots)
        #pragma unroll
        for (int dt = 0; dt < 8; ++dt) {
            bf16x8 vb0 = ldsfrag2(&Vt[gsel][dt*16 + l15][quad * 8]);
            oacc[dt] = MFMA16(pa0, vb0, oacc[dt]);
            bf16x8 vb1 = ldsfrag2(&Vt[gsel][dt*16 + l15][32 + quad * 8]);
            oacc[dt] = MFMA16(pa1, vb1, oacc[dt]);
        }
    }

    // each wave owns its (g, rep) head over the full chunk: write partials directly
    const size_t obase = (size_t)((b * 8 + g) * 8 + c) * 64 + rep * 16 + quad * 4;
    #pragma unroll
    for (int dt = 0; dt < 8; ++dt)
        #pragma unroll
        for (int r = 0; r < 4; ++r)
            part_O[(obase + r) * HD + dt * 16 + l15] = oacc[dt][r];
    if (l15 == 0) {
        #pragma unroll
        for (int r = 0; r < 4; ++r) {
            part_m[obase + r] = m_run[r];
            part_l[obase + r] = l_run[r];
        }
    }
}

__global__ __launch_bounds__(128) void attn_combine_kernel(
    const float* __restrict__ part_O, const float* __restrict__ part_m,
    const float* __restrict__ part_l, unsigned short* __restrict__ ah,
    unsigned short* __restrict__ al)
{
    int bid = blockIdx.x;          // (b*8+g)*64 + row
    int d = threadIdx.x;
    int bg = bid >> 6;
    int row = bid & 63;
    float mc[NCHUNK], lc[NCHUNK];
    float M = -INFINITY;
    #pragma unroll
    for (int cc = 0; cc < NCHUNK; ++cc) {
        mc[cc] = part_m[(bg * NCHUNK + cc) * 64 + row];
        lc[cc] = part_l[(bg * NCHUNK + cc) * 64 + row];
        M = fmaxf(M, mc[cc]);
    }
    float L = 0.f, acc = 0.f;
    #pragma unroll
    for (int cc = 0; cc < NCHUNK; ++cc) {
        float wgt = __expf(mc[cc] - M);
        L += lc[cc] * wgt;
        acc += part_O[((size_t)(bg * NCHUNK + cc) * 64 + row) * HD + d] * wgt;
    }
    int b = bg >> 3, g = bg & 7;
    int r = row >> 4, qp = row & 15;
    float v = acc / L;
    unsigned short h, l; splitbf(v, h, l);
    size_t idx = (size_t)(b * 16 + qp) * DIM + (g * 4 + r) * HD + d;
    ah[idx] = h; al[idx] = l;
}

__global__ __launch_bounds__(256) void oproj_reduce_kernel(
    const float* __restrict__ part, const float* __restrict__ bo,
    float* __restrict__ out)
{
    int gid4 = blockIdx.x * 256 + threadIdx.x;   // < 128*1024 (float4 units)
    int n = (gid4 & 1023) * 4;
    float4 s = make_float4(0.f, 0.f, 0.f, 0.f);
    #pragma unroll
    for (int j = 0; j < KS; ++j) {
        float4 p = *(const float4*)&part[(size_t)j * 524288 + (size_t)gid4 * 4];
        s.x += p.x; s.y += p.y; s.z += p.z; s.w += p.w;
    }
    float4 b4 = *(const float4*)&bo[n];
    float4 o = make_float4(s.x + b4.x, s.y + b4.y, s.z + b4.z, s.w + b4.w);
    *(float4*)&out[(size_t)gid4 * 4] = o;
}

extern "C" void kernel_launch(void* const* d_in, const int* in_sizes, int n_in,
                              void* d_out, int out_size, void* d_ws, size_t ws_size,
                              hipStream_t stream)
{
    const float* x  = (const float*)d_in[0];
    const float* kc = (const float*)d_in[1];
    const float* vc = (const float*)d_in[2];
    const float* Wq = (const float*)d_in[3];
    const float* bq = (const float*)d_in[4];
    const float* Wk = (const float*)d_in[5];
    const float* bk = (const float*)d_in[6];
    const float* Wv = (const float*)d_in[7];
    const float* bv = (const float*)d_in[8];
    const float* Wo = (const float*)d_in[9];
    const float* bo = (const float*)d_in[10];
    float* out = (float*)d_out;
    float* ws  = (float*)d_ws;

    unsigned short* xh = (unsigned short*)(ws + WS_XH);
    unsigned short* xl = (unsigned short*)(ws + WS_XL);
    unsigned short* qh = (unsigned short*)(ws + WS_QH);
    unsigned short* ql = (unsigned short*)(ws + WS_QL);
    unsigned short* ath = (unsigned short*)(ws + WS_ATH);
    unsigned short* atl = (unsigned short*)(ws + WS_ATL);

    split_x_kernel<<<512, 256, 0, stream>>>(x, xh, xl, 131072);
    qkv_gemm_kernel<<<dim3(96, KS), 256, 0, stream>>>(xh, xl, Wq, Wk, Wv, ws + WS_PART);
    qkv_reduce_kernel<<<768, 256, 0, stream>>>(ws + WS_PART, bq, bk, bv,
                                               qh, ql, ws + WS_KNEW, ws + WS_VNEW);
    attn_partial7_kernel<<<256, 512, 0, stream>>>(qh, ql, kc, vc,
                                                  ws + WS_KNEW, ws + WS_VNEW,
                                                  ws + WS_PARTO, ws + WS_PM, ws + WS_PL);
    attn_combine_kernel<<<4096, 128, 0, stream>>>(ws + WS_PARTO, ws + WS_PM,
                                                  ws + WS_PL, ath, atl);
    oproj_gemm_kernel<<<dim3(64, KS), 256, 0, stream>>>(ath, atl, Wo, ws + WS_PART);
    oproj_reduce_kernel<<<512, 256, 0, stream>>>(ws + WS_PART, bo, out);
}